// Round 10
// baseline (1112.086 us; speedup 1.0000x reference)
//
#include <hip/hip_runtime.h>
#include <hip/hip_bf16.h>
#include <hip/hip_cooperative_groups.h>

namespace cg = cooperative_groups;

// Problem constants (fixed by the reference setup)
#define NN 50000     // nodes
#define NE 800000    // edges
#define FD 128       // feature dim (D_FEAT == DIM_H)
#define NG 512       // graphs
#define NC 10        // classes
#define NL 3         // layers
#define SCAN_B 196   // ceil(NN/256)
#define WT_B 192     // NL*FD*FD/256

typedef unsigned short u16;
typedef unsigned int u32;
typedef short bf16x8 __attribute__((ext_vector_type(8)));
typedef float f32x4 __attribute__((ext_vector_type(4)));

__device__ __forceinline__ float b2f(u16 v) {
    union { u32 u; float f; } c; c.u = ((u32)v) << 16; return c.f;
}
__device__ __forceinline__ u16 f2b(float f) {
    __hip_bfloat16 h = __float2bfloat16(f);   // RTNE
    return *(u16*)&h;
}

// ======== LEAN cooperative CSR builder: zero+deg+dinv+scan+fill ========
// No MFMA / no fat phases -> low VGPR -> 8 blocks/CU co-resident at 2048 blocks.
// (Round 9 lesson: coop fusion must keep full occupancy for atomic phases.)
__global__ __launch_bounds__(256) void k_csr(const float* __restrict__ W,
                                             const int* __restrict__ src,
                                             const int* __restrict__ dst,
                                             u16* __restrict__ WT,
                                             int* __restrict__ deg,
                                             float* __restrict__ dinv,
                                             int* __restrict__ bsum,
                                             int* __restrict__ rowst,
                                             int* __restrict__ pos,
                                             int* __restrict__ csr_s) {
    cg::grid_group grid = cg::this_grid();
    __shared__ int sb[256];
    const int tid = threadIdx.x;
    const int bid = blockIdx.x;
    const int gtid = bid * 256 + tid;
    const int total = gridDim.x * 256;

    // --- phase A: WT transpose-convert + deg zero ---
    for (int i = gtid; i < NL * FD * FD; i += total) {
        const int l = i >> 14, r = i & 16383, k = r >> 7, n = r & 127;
        WT[(l << 14) + n * FD + k] = f2b(W[i]);
    }
    for (int n = gtid; n < NN; n += total) deg[n] = 0;
    grid.sync();

    // --- phase B: degree atomics (full occupancy) ---
    for (int e = gtid; e < NE; e += total) atomicAdd(&deg[dst[e]], 1);
    grid.sync();

    // --- phase C: dinv + per-chunk local scan ---
    for (int n = gtid; n < NN; n += total)
        dinv[n] = rsqrtf((float)(deg[n] + 1));         // +1 = self loop
    int excl = 0;
    if (bid < SCAN_B) {
        const int i = bid * 256 + tid;
        const int v = (i < NN) ? deg[i] : 0;
        sb[tid] = v;
        __syncthreads();
        for (int off = 1; off < 256; off <<= 1) {
            int t = (tid >= off) ? sb[tid - off] : 0;
            __syncthreads();
            sb[tid] += t;
            __syncthreads();
        }
        excl = sb[tid] - v;                            // exclusive local
        if (tid == 255) bsum[bid] = sb[255];
    }
    grid.sync();

    // --- phase D: cross-chunk offsets -> rowst/pos ---
    if (bid < SCAN_B) {
        const int i = bid * 256 + tid;
        const int bv = (tid < SCAN_B) ? bsum[tid] : 0;
        sb[tid] = bv;
        __syncthreads();
        for (int off = 1; off < 256; off <<= 1) {
            int t = (tid >= off) ? sb[tid - off] : 0;
            __syncthreads();
            sb[tid] += t;
            __syncthreads();
        }
        const int boffv = sb[bid] - bsum[bid];         // exclusive block offset
        if (i < NN) {
            const int e0 = boffv + excl;
            rowst[i] = e0;
            pos[i] = e0;
        }
        if (gtid == 0) rowst[NN] = NE;
    }
    grid.sync();

    // --- phase E: CSR fill (src-only, full occupancy) ---
    for (int e = gtid; e < NE; e += total) {
        const int s = src[e];
        const int d = dst[e];
        const int slot = atomicAdd(&pos[d], 1);
        csr_s[slot] = s;
    }
}

// ======== gemm0 tile body: 16 rows of x(fp32) @ W0 -> B0(bf16) ========
// a_frag: A[m=lane&15][k=q*8+j]; b_frag: W[k=q*8+j][n=lane&15];
// C/D: col=lane&15, row=q*4+reg   [verified m89/m91; rounds 6-8]
__device__ __forceinline__ void gemm0_tile(const int row0, const int lane,
                                           const float* __restrict__ x,
                                           const u16* __restrict__ WT,
                                           u16* __restrict__ Bout) {
    const int m = lane & 15;
    const int q = lane >> 4;
    f32x4 acc[8];
#pragma unroll
    for (int ct = 0; ct < 8; ++ct) acc[ct] = (f32x4){0.f, 0.f, 0.f, 0.f};
    const float* arow = x + (size_t)(row0 + m) * FD + q * 8;
    const u16* wrow = WT + (size_t)m * FD + q * 8;
#pragma unroll
    for (int kb = 0; kb < 4; ++kb) {
        const float4 p0 = *(const float4*)(arow + kb * 32);
        const float4 p1 = *(const float4*)(arow + kb * 32 + 4);
        bf16x8 af;
        af[0] = (short)f2b(p0.x); af[1] = (short)f2b(p0.y);
        af[2] = (short)f2b(p0.z); af[3] = (short)f2b(p0.w);
        af[4] = (short)f2b(p1.x); af[5] = (short)f2b(p1.y);
        af[6] = (short)f2b(p1.z); af[7] = (short)f2b(p1.w);
#pragma unroll
        for (int ct = 0; ct < 8; ++ct) {
            bf16x8 bf = *(const bf16x8*)(wrow + (size_t)ct * 16 * FD + kb * 32);
            acc[ct] = __builtin_amdgcn_mfma_f32_16x16x32_bf16(af, bf, acc[ct], 0, 0, 0);
        }
    }
#pragma unroll
    for (int ct = 0; ct < 8; ++ct)
#pragma unroll
        for (int r = 0; r < 4; ++r)
            Bout[(size_t)(row0 + q * 4 + r) * FD + ct * 16 + m] = f2b(acc[ct][r]);
}

__global__ __launch_bounds__(256) void k_gemm0(const float* __restrict__ x,
                                               const u16* __restrict__ WT,
                                               u16* __restrict__ Bout) {
    const int wid = blockIdx.x * 4 + (threadIdx.x >> 6);
    if (wid >= 3125) return;
    gemm0_tile(wid * 16, threadIdx.x & 63, x, WT, Bout);
}

// ======== discrete fallback kernels (if cooperative launch refused) ========
__global__ __launch_bounds__(256) void k_prep(const float* __restrict__ W,
                                              u16* __restrict__ wt,
                                              int* __restrict__ deg) {
    const int bid = blockIdx.x;
    if (bid < WT_B) {
        const int i = bid * 256 + threadIdx.x;
        const int l = i >> 14, r = i & 16383, k = r >> 7, n = r & 127;
        wt[(l << 14) + n * FD + k] = f2b(W[i]);
    } else {
        const int n = (bid - WT_B) * 256 + threadIdx.x;
        if (n < NN) deg[n] = 0;
    }
}
__global__ __launch_bounds__(256) void k_deg(const int* __restrict__ dst,
                                             int* __restrict__ deg) {
    const int e = blockIdx.x * 256 + threadIdx.x;
    atomicAdd(&deg[dst[e]], 1);
}
__global__ __launch_bounds__(256) void k_degfin(const int* __restrict__ deg,
                                                float* __restrict__ dinv,
                                                int* __restrict__ bsum) {
    __shared__ int sb[256];
    const int i = blockIdx.x * 256 + threadIdx.x;
    const int v = (i < NN) ? deg[i] : 0;
    if (i < NN) dinv[i] = rsqrtf((float)(v + 1));
    sb[threadIdx.x] = v;
    __syncthreads();
    for (int off = 128; off > 0; off >>= 1) {
        if (threadIdx.x < off) sb[threadIdx.x] += sb[threadIdx.x + off];
        __syncthreads();
    }
    if (threadIdx.x == 0) bsum[blockIdx.x] = sb[0];
}
__global__ __launch_bounds__(256) void k_scan(const int* __restrict__ deg,
                                              const int* __restrict__ bsum,
                                              int* __restrict__ rowst,
                                              int* __restrict__ pos) {
    __shared__ int sb[256];
    const int tid = threadIdx.x;
    const int i = blockIdx.x * 256 + tid;
    const int bv = (tid < SCAN_B) ? bsum[tid] : 0;
    sb[tid] = bv;
    __syncthreads();
    for (int off = 1; off < 256; off <<= 1) {
        int t = (tid >= off) ? sb[tid - off] : 0;
        __syncthreads();
        sb[tid] += t;
        __syncthreads();
    }
    const int boffv = sb[blockIdx.x] - bsum[blockIdx.x];
    __syncthreads();
    const int v = (i < NN) ? deg[i] : 0;
    sb[tid] = v;
    __syncthreads();
    for (int off = 1; off < 256; off <<= 1) {
        int t = (tid >= off) ? sb[tid - off] : 0;
        __syncthreads();
        sb[tid] += t;
        __syncthreads();
    }
    if (i < NN) {
        const int excl = boffv + sb[tid] - v;
        rowst[i] = excl;
        pos[i] = excl;
    }
    if (i == 0) rowst[NN] = NE;
}
__global__ __launch_bounds__(256) void k_fill(const int* __restrict__ src,
                                              const int* __restrict__ dst,
                                              int* __restrict__ pos,
                                              int* __restrict__ csr_s) {
    const int e = blockIdx.x * 256 + threadIdx.x;
    const int s = src[e];
    const int d = dst[e];
    const int slot = atomicAdd(&pos[d], 1);
    csr_s[slot] = s;
}

// ======== per-wave gather body: relu(di*(sum + di*self) + bias) ========
__device__ __forceinline__ float2 gather_node(const int rs, const int re,
                                              const int* __restrict__ csr_s,
                                              const u16* __restrict__ B,
                                              const float* __restrict__ dinv,
                                              const float di, const int n,
                                              const float2 bb, const int f) {
    const ushort2 vs = *(const ushort2*)(B + (size_t)n * FD + f);
    float a0 = 0.f, a1 = 0.f, b0 = 0.f, b1 = 0.f;
    float c0 = 0.f, c1 = 0.f, d0 = 0.f, d1 = 0.f;
    int e = rs;
    for (; e + 8 <= re; e += 8) {                     // 8-edge unroll for MLP
        int s[8]; float w[8]; ushort2 v[8];
#pragma unroll
        for (int j = 0; j < 8; ++j) s[j] = csr_s[e + j];
#pragma unroll
        for (int j = 0; j < 8; ++j) w[j] = dinv[s[j]];
#pragma unroll
        for (int j = 0; j < 8; ++j)
            v[j] = *(const ushort2*)(B + (size_t)s[j] * FD + f);
        a0 += b2f(v[0].x) * w[0]; a1 += b2f(v[0].y) * w[0];
        b0 += b2f(v[1].x) * w[1]; b1 += b2f(v[1].y) * w[1];
        c0 += b2f(v[2].x) * w[2]; c1 += b2f(v[2].y) * w[2];
        d0 += b2f(v[3].x) * w[3]; d1 += b2f(v[3].y) * w[3];
        a0 += b2f(v[4].x) * w[4]; a1 += b2f(v[4].y) * w[4];
        b0 += b2f(v[5].x) * w[5]; b1 += b2f(v[5].y) * w[5];
        c0 += b2f(v[6].x) * w[6]; c1 += b2f(v[6].y) * w[6];
        d0 += b2f(v[7].x) * w[7]; d1 += b2f(v[7].y) * w[7];
    }
    for (; e + 4 <= re; e += 4) {
        int s[4]; float w[4]; ushort2 v[4];
#pragma unroll
        for (int j = 0; j < 4; ++j) s[j] = csr_s[e + j];
#pragma unroll
        for (int j = 0; j < 4; ++j) w[j] = dinv[s[j]];
#pragma unroll
        for (int j = 0; j < 4; ++j)
            v[j] = *(const ushort2*)(B + (size_t)s[j] * FD + f);
        a0 += b2f(v[0].x) * w[0]; a1 += b2f(v[0].y) * w[0];
        b0 += b2f(v[1].x) * w[1]; b1 += b2f(v[1].y) * w[1];
        c0 += b2f(v[2].x) * w[2]; c1 += b2f(v[2].y) * w[2];
        d0 += b2f(v[3].x) * w[3]; d1 += b2f(v[3].y) * w[3];
    }
    for (; e < re; ++e) {
        const int s0 = csr_s[e];
        const float w0 = dinv[s0];
        const ushort2 v0 = *(const ushort2*)(B + (size_t)s0 * FD + f);
        a0 += b2f(v0.x) * w0; a1 += b2f(v0.y) * w0;
    }
    a0 += b0 + c0 + d0 + b2f(vs.x) * di;   // self loop: dinv[n]*B[n]
    a1 += b1 + c1 + d1 + b2f(vs.y) * di;
    float2 r;
    r.x = fmaxf(a0 * di + bb.x, 0.f);      // w_e = dinv[s]*dinv[n] folded
    r.y = fmaxf(a1 * di + bb.y, 0.f);
    return r;
}

// ======== fused gather(l) + gemm(l+1): 16 waves gather -> 8 waves MFMA ====
__global__ __launch_bounds__(1024) void k_gg(const int* __restrict__ rowst,
                                             const int* __restrict__ csr_s,
                                             const u16* __restrict__ Bin,
                                             const float* __restrict__ dinv,
                                             const float* __restrict__ bias,
                                             const u16* __restrict__ WTn,
                                             u16* __restrict__ Bout) {
    __shared__ u16 sA[16][FD + 8];   // +16B row pad: conflicts 16-way -> free 2-way
    const int tid = threadIdx.x;
    const int wave = tid >> 6;       // 0..15
    const int lane = tid & 63;
    const int nb = blockIdx.x * 16;  // 3125 blocks exact
    {
        const int n = nb + wave;
        const int f = lane * 2;
        const int rs = rowst[n];
        const int re = rowst[n + 1];
        const float di = dinv[n];
        const float2 bb = *(const float2*)(bias + f);
        const float2 r = gather_node(rs, re, csr_s, Bin, dinv, di, n, bb, f);
        ushort2 o; o.x = f2b(r.x); o.y = f2b(r.y);
        *(ushort2*)&sA[wave][f] = o;
    }
    __syncthreads();
    if (wave >= 8) return;
    const int ct = wave;
    const int m = lane & 15;
    const int q = lane >> 4;
    f32x4 acc = (f32x4){0.f, 0.f, 0.f, 0.f};
    const u16* wrow = WTn + (size_t)m * FD + q * 8 + (size_t)ct * 16 * FD;
#pragma unroll
    for (int kb = 0; kb < 4; ++kb) {
        bf16x8 af = *(const bf16x8*)&sA[m][q * 8 + kb * 32];
        bf16x8 bf = *(const bf16x8*)(wrow + kb * 32);
        acc = __builtin_amdgcn_mfma_f32_16x16x32_bf16(af, bf, acc, 0, 0, 0);
    }
#pragma unroll
    for (int r = 0; r < 4; ++r)
        Bout[(size_t)(nb + q * 4 + r) * FD + ct * 16 + m] = f2b(acc[r]);
}

// ======== final gather (layer 2) -> Ab bf16 ========
__global__ __launch_bounds__(256) void k_gather(const int* __restrict__ rowst,
                                                const int* __restrict__ csr_s,
                                                const u16* __restrict__ B,
                                                const float* __restrict__ dinv,
                                                const float* __restrict__ bias,
                                                u16* __restrict__ Ab) {
    const int gid = blockIdx.x * 256 + threadIdx.x;   // NN*64 threads exact
    const int n = gid >> 6;
    const int f = (gid & 63) * 2;
    const int rs = rowst[n];
    const int re = rowst[n + 1];
    const float di = dinv[n];
    const float2 bb = *(const float2*)(bias + f);
    const float2 r = gather_node(rs, re, csr_s, B, dinv, di, n, bb, f);
    ushort2 o; o.x = f2b(r.x); o.y = f2b(r.y);
    *(ushort2*)(Ab + (size_t)n * FD + f) = o;
}

// ======== fused mean-pool + linear head + log_softmax (1 block / graph) ====
__global__ __launch_bounds__(256) void k_poolhead(const u16* __restrict__ Ab,
                                                  const int* __restrict__ batch,
                                                  const float* __restrict__ lin_w,
                                                  const float* __restrict__ lin_b,
                                                  float* __restrict__ out) {
    __shared__ float sb[256];
    __shared__ float hm[FD];
    __shared__ int bnd[2];
    __shared__ float part2[2 * NC];
    const int g = blockIdx.x;                          // NG blocks
    const int tid = threadIdx.x;
    if (tid < 2) {
        const int key = g + tid;
        int lo = 0, hi = NN;
        while (lo < hi) {
            const int mid = (lo + hi) >> 1;
            if (batch[mid] < key) lo = mid + 1; else hi = mid;
        }
        bnd[tid] = lo;
    }
    __syncthreads();
    const int r0 = bnd[0], r1 = bnd[1];
    const int f = tid & 127;
    const int half = tid >> 7;
    float acc = 0.f;
    for (int r = r0 + half; r < r1; r += 2)
        acc += b2f(Ab[(size_t)r * FD + f]);
    sb[tid] = acc;
    __syncthreads();
    if (tid < 128) {
        const float mean = (sb[tid] + sb[tid + 128]) /
                           fmaxf((float)(r1 - r0), 1.0f);
        hm[tid] = mean;
        out[(size_t)g * FD + tid] = mean;
    }
    __syncthreads();
    if (tid < 128) {
        const float hv = hm[tid];
        const int wv = tid >> 6;
#pragma unroll
        for (int c = 0; c < NC; ++c) {
            float p = hv * lin_w[tid * NC + c];
#pragma unroll
            for (int o = 32; o > 0; o >>= 1) p += __shfl_down(p, o, 64);
            if ((tid & 63) == 0) part2[c * 2 + wv] = p;
        }
    }
    __syncthreads();
    if (tid == 0) {
        float lg[NC];
        float m = -1e30f;
#pragma unroll
        for (int c = 0; c < NC; ++c) {
            lg[c] = part2[2 * c] + part2[2 * c + 1] + lin_b[c];
            m = fmaxf(m, lg[c]);
        }
        float s = 0.f;
#pragma unroll
        for (int c = 0; c < NC; ++c) s += expf(lg[c] - m);
        const float lse = m + logf(s);
        float* o = out + (size_t)NG * FD + (size_t)g * NC;
#pragma unroll
        for (int c = 0; c < NC; ++c) o[c] = lg[c] - lse;
    }
}

extern "C" void kernel_launch(void* const* d_in, const int* in_sizes, int n_in,
                              void* d_out, int out_size, void* d_ws, size_t ws_size,
                              hipStream_t stream) {
    const float* x     = (const float*)d_in[0];   // [NN,128] fp32
    const float* W     = (const float*)d_in[1];   // [3,128,128] fp32
    const float* bias  = (const float*)d_in[2];   // [3,128] fp32
    const float* lin_w = (const float*)d_in[3];   // [128,10] fp32
    const float* lin_b = (const float*)d_in[4];   // [10] fp32
    const int*   src   = (const int*)d_in[5];     // edge_index[0], int32
    const int*   dst   = src + NE;                // edge_index[1]
    const int*   batch = (const int*)d_in[6];     // [NN] int32

    // workspace layout (~43 MB), all chunks 16B-aligned
    u16*   B0     = (u16*)d_ws;                       // NN*FD bf16
    u16*   B1     = B0 + (size_t)NN * FD;             // NN*FD bf16
    u16*   Ab     = B1 + (size_t)NN * FD;             // NN*FD bf16 (final h)
    u16*   WT     = Ab + (size_t)NN * FD;             // NL*FD*FD bf16 (transposed)
    int*   csr_s  = (int*)(WT + (size_t)NL * FD * FD); // NE src-only
    int*   deg    = csr_s + NE;                       // NN
    int*   rowst  = deg + NN;                         // NN+1 (+3 pad)
    int*   pos    = rowst + NN + 4;                   // NN
    int*   bsum   = pos + NN;                         // 256
    float* dinv   = (float*)(bsum + 256);             // NN
    float* out    = (float*)d_out;                    // hG [NG*FD] ++ logsm [NG*NC]

    // --- CSR build: one lean cooperative launch at FULL occupancy ---
    {
        void* args[] = {(void*)&W, (void*)&src, (void*)&dst, (void*)&WT,
                        (void*)&deg, (void*)&dinv, (void*)&bsum,
                        (void*)&rowst, (void*)&pos, (void*)&csr_s};
        hipError_t err = hipLaunchCooperativeKernel(
            (const void*)k_csr, dim3(2048), dim3(256), args, 0, stream);
        if (err != hipSuccess) {
            (void)hipGetLastError();
            err = hipLaunchCooperativeKernel(
                (const void*)k_csr, dim3(1024), dim3(256), args, 0, stream);
        }
        if (err != hipSuccess) {
            (void)hipGetLastError();   // discrete fallback (Round 8 chain)
            k_prep<<<WT_B + SCAN_B, 256, 0, stream>>>(W, WT, deg);
            k_deg<<<NE / 256, 256, 0, stream>>>(dst, deg);
            k_degfin<<<SCAN_B, 256, 0, stream>>>(deg, dinv, bsum);
            k_scan<<<SCAN_B, 256, 0, stream>>>(deg, bsum, rowst, pos);
            k_fill<<<NE / 256, 256, 0, stream>>>(src, dst, pos, csr_s);
        }
    }

    // --- layers: gemm0; fused gather+gemm x2; final gather ---
    k_gemm0<<<(3125 + 3) / 4, 256, 0, stream>>>(x, WT, B0);
    k_gg<<<NN / 16, 1024, 0, stream>>>(rowst, csr_s, B0, dinv, bias,
                                       WT + (size_t)1 * FD * FD, B1);
    k_gg<<<NN / 16, 1024, 0, stream>>>(rowst, csr_s, B1, dinv, bias + FD,
                                       WT + (size_t)2 * FD * FD, B0);
    k_gather<<<NN * 64 / 256, 256, 0, stream>>>(rowst, csr_s, B0, dinv,
                                                bias + 2 * FD, Ab);

    // --- fused mean pool + head ---
    k_poolhead<<<NG, 256, 0, stream>>>(Ab, batch, lin_w, lin_b, out);
}

// Round 11
// 382.830 us; speedup vs baseline: 2.9049x; 2.9049x over previous
//
#include <hip/hip_runtime.h>
#include <hip/hip_bf16.h>

// Problem constants (fixed by the reference setup)
#define NN 50000     // nodes
#define NE 800000    // edges
#define FD 128       // feature dim (D_FEAT == DIM_H)
#define NG 512       // graphs
#define NC 10        // classes
#define NL 3         // layers
#define SCAN_B 196   // ceil(NN/256)
#define WT_B 192     // NL*FD*FD/256
#define FILL_B 3125  // NE/256
#define GEMM_B 782   // ceil(3125/4)

typedef unsigned short u16;
typedef unsigned int u32;
typedef short bf16x8 __attribute__((ext_vector_type(8)));
typedef float f32x4 __attribute__((ext_vector_type(4)));

__device__ __forceinline__ float b2f(u16 v) {
    union { u32 u; float f; } c; c.u = ((u32)v) << 16; return c.f;
}
__device__ __forceinline__ u16 f2b(float f) {
    __hip_bfloat16 h = __float2bfloat16(f);   // RTNE
    return *(u16*)&h;
}

// ======== prep: WT convert + deg zero + agg init (one dispatch) ========
__global__ __launch_bounds__(256) void k_prep(const float* __restrict__ W,
                                              u16* __restrict__ wt,
                                              int* __restrict__ deg,
                                              int* __restrict__ agg) {
    const int bid = blockIdx.x;
    if (bid < WT_B) {
        const int i = bid * 256 + threadIdx.x;        // NL*FD*FD exact
        const int l = i >> 14, r = i & 16383, k = r >> 7, n = r & 127;
        wt[(l << 14) + n * FD + k] = f2b(W[i]);
    } else if (bid < WT_B + SCAN_B) {
        const int n = (bid - WT_B) * 256 + threadIdx.x;
        if (n < NN) deg[n] = 0;
    } else {
        if (threadIdx.x < SCAN_B) agg[threadIdx.x] = -1;   // lookback init
    }
}

// ======== degree atomics ========
__global__ __launch_bounds__(256) void k_deg(const int* __restrict__ dst,
                                             int* __restrict__ deg) {
    const int e = blockIdx.x * 256 + threadIdx.x;     // NE threads exact
    atomicAdd(&deg[dst[e]], 1);
}

// ======== dinv + exclusive scan via decoupled lookback (ONE dispatch) ======
// 196 blocks <= 256 CUs -> all co-resident; each block publishes its local
// aggregate then spin-reads predecessors in parallel (one per lane).
__global__ __launch_bounds__(256) void k_scanf(const int* __restrict__ deg,
                                               float* __restrict__ dinv,
                                               int* __restrict__ agg,
                                               int* __restrict__ rowst,
                                               int* __restrict__ pos) {
    __shared__ int sb[256];
    const int tid = threadIdx.x;
    const int bid = blockIdx.x;
    const int i = bid * 256 + tid;
    const int v = (i < NN) ? deg[i] : 0;
    if (i < NN) dinv[i] = rsqrtf((float)(v + 1));     // +1 = self loop
    // local inclusive scan
    sb[tid] = v;
    __syncthreads();
    for (int off = 1; off < 256; off <<= 1) {
        int t = (tid >= off) ? sb[tid - off] : 0;
        __syncthreads();
        sb[tid] += t;
        __syncthreads();
    }
    const int excl = sb[tid] - v;
    const int aggregate = sb[255];
    __syncthreads();
    // publish own aggregate (device-scope atomic; visible to all XCDs)
    if (tid == 0) atomicExch(&agg[bid], aggregate);
    // parallel lookback: lane t spins on predecessor t
    int a = 0;
    if (tid < bid) {
        do { a = atomicAdd(&agg[tid], 0); } while (a < 0);
    }
    sb[tid] = a;
    __syncthreads();
    for (int off = 128; off > 0; off >>= 1) {
        if (tid < off) sb[tid] += sb[tid + off];
        __syncthreads();
    }
    const int prefix = sb[0];
    if (i < NN) {
        const int e0 = prefix + excl;
        rowst[i] = e0;
        pos[i] = e0;
    }
    if (i == 0) rowst[NN] = NE;   // every edge has a dst
}

// ======== gemm0 tile body: 16 rows of x(fp32) @ W0 -> B0(bf16) ========
// a_frag: A[m=lane&15][k=q*8+j]; b_frag: W[k=q*8+j][n=lane&15];
// C/D: col=lane&15, row=q*4+reg   [verified m89/m91; rounds 6-8]
__device__ __forceinline__ void gemm0_tile(const int row0, const int lane,
                                           const float* __restrict__ x,
                                           const u16* __restrict__ WT,
                                           u16* __restrict__ Bout) {
    const int m = lane & 15;
    const int q = lane >> 4;
    f32x4 acc[8];
#pragma unroll
    for (int ct = 0; ct < 8; ++ct) acc[ct] = (f32x4){0.f, 0.f, 0.f, 0.f};
    const float* arow = x + (size_t)(row0 + m) * FD + q * 8;
    const u16* wrow = WT + (size_t)m * FD + q * 8;
#pragma unroll
    for (int kb = 0; kb < 4; ++kb) {
        const float4 p0 = *(const float4*)(arow + kb * 32);
        const float4 p1 = *(const float4*)(arow + kb * 32 + 4);
        bf16x8 af;
        af[0] = (short)f2b(p0.x); af[1] = (short)f2b(p0.y);
        af[2] = (short)f2b(p0.z); af[3] = (short)f2b(p0.w);
        af[4] = (short)f2b(p1.x); af[5] = (short)f2b(p1.y);
        af[6] = (short)f2b(p1.z); af[7] = (short)f2b(p1.w);
#pragma unroll
        for (int ct = 0; ct < 8; ++ct) {
            bf16x8 bf = *(const bf16x8*)(wrow + (size_t)ct * 16 * FD + kb * 32);
            acc[ct] = __builtin_amdgcn_mfma_f32_16x16x32_bf16(af, bf, acc[ct], 0, 0, 0);
        }
    }
#pragma unroll
    for (int ct = 0; ct < 8; ++ct)
#pragma unroll
        for (int r = 0; r < 4; ++r)
            Bout[(size_t)(row0 + q * 4 + r) * FD + ct * 16 + m] = f2b(acc[ct][r]);
}

// ======== fused CSR fill + gemm0 (independent work, disjoint blocks) ======
__global__ __launch_bounds__(256) void k_fillgemm(const int* __restrict__ src,
                                                  const int* __restrict__ dst,
                                                  int* __restrict__ pos,
                                                  int* __restrict__ csr_s,
                                                  const float* __restrict__ x,
                                                  const u16* __restrict__ WT,
                                                  u16* __restrict__ B0) {
    const int bid = blockIdx.x;
    if (bid < FILL_B) {
        const int e = bid * 256 + threadIdx.x;        // NE exact
        const int s = src[e];
        const int d = dst[e];
        const int slot = atomicAdd(&pos[d], 1);
        csr_s[slot] = s;
    } else {
        const int wid = (bid - FILL_B) * 4 + (threadIdx.x >> 6);
        if (wid >= 3125) return;
        gemm0_tile(wid * 16, threadIdx.x & 63, x, WT, B0);
    }
}

// ======== per-wave gather body: relu(di*(sum + di*self) + bias) ========
__device__ __forceinline__ float2 gather_node(const int rs, const int re,
                                              const int* __restrict__ csr_s,
                                              const u16* __restrict__ B,
                                              const float* __restrict__ dinv,
                                              const float di, const int n,
                                              const float2 bb, const int f) {
    const ushort2 vs = *(const ushort2*)(B + (size_t)n * FD + f);
    float a0 = 0.f, a1 = 0.f, b0 = 0.f, b1 = 0.f;
    float c0 = 0.f, c1 = 0.f, d0 = 0.f, d1 = 0.f;
    int e = rs;
    for (; e + 8 <= re; e += 8) {                     // 8-edge unroll for MLP
        int s[8]; float w[8]; ushort2 v[8];
#pragma unroll
        for (int j = 0; j < 8; ++j) s[j] = csr_s[e + j];
#pragma unroll
        for (int j = 0; j < 8; ++j) w[j] = dinv[s[j]];
#pragma unroll
        for (int j = 0; j < 8; ++j)
            v[j] = *(const ushort2*)(B + (size_t)s[j] * FD + f);
        a0 += b2f(v[0].x) * w[0]; a1 += b2f(v[0].y) * w[0];
        b0 += b2f(v[1].x) * w[1]; b1 += b2f(v[1].y) * w[1];
        c0 += b2f(v[2].x) * w[2]; c1 += b2f(v[2].y) * w[2];
        d0 += b2f(v[3].x) * w[3]; d1 += b2f(v[3].y) * w[3];
        a0 += b2f(v[4].x) * w[4]; a1 += b2f(v[4].y) * w[4];
        b0 += b2f(v[5].x) * w[5]; b1 += b2f(v[5].y) * w[5];
        c0 += b2f(v[6].x) * w[6]; c1 += b2f(v[6].y) * w[6];
        d0 += b2f(v[7].x) * w[7]; d1 += b2f(v[7].y) * w[7];
    }
    for (; e + 4 <= re; e += 4) {
        int s[4]; float w[4]; ushort2 v[4];
#pragma unroll
        for (int j = 0; j < 4; ++j) s[j] = csr_s[e + j];
#pragma unroll
        for (int j = 0; j < 4; ++j) w[j] = dinv[s[j]];
#pragma unroll
        for (int j = 0; j < 4; ++j)
            v[j] = *(const ushort2*)(B + (size_t)s[j] * FD + f);
        a0 += b2f(v[0].x) * w[0]; a1 += b2f(v[0].y) * w[0];
        b0 += b2f(v[1].x) * w[1]; b1 += b2f(v[1].y) * w[1];
        c0 += b2f(v[2].x) * w[2]; c1 += b2f(v[2].y) * w[2];
        d0 += b2f(v[3].x) * w[3]; d1 += b2f(v[3].y) * w[3];
    }
    for (; e < re; ++e) {
        const int s0 = csr_s[e];
        const float w0 = dinv[s0];
        const ushort2 v0 = *(const ushort2*)(B + (size_t)s0 * FD + f);
        a0 += b2f(v0.x) * w0; a1 += b2f(v0.y) * w0;
    }
    a0 += b0 + c0 + d0 + b2f(vs.x) * di;   // self loop: dinv[n]*B[n]
    a1 += b1 + c1 + d1 + b2f(vs.y) * di;
    float2 r;
    r.x = fmaxf(a0 * di + bb.x, 0.f);      // w_e = dinv[s]*dinv[n] folded
    r.y = fmaxf(a1 * di + bb.y, 0.f);
    return r;
}

// ======== fused gather(l) + gemm(l+1): 16 waves gather -> 8 waves MFMA ====
__global__ __launch_bounds__(1024) void k_gg(const int* __restrict__ rowst,
                                             const int* __restrict__ csr_s,
                                             const u16* __restrict__ Bin,
                                             const float* __restrict__ dinv,
                                             const float* __restrict__ bias,
                                             const u16* __restrict__ WTn,
                                             u16* __restrict__ Bout) {
    __shared__ u16 sA[16][FD + 8];   // +16B row pad: break 16-way LDS conflicts
    const int tid = threadIdx.x;
    const int wave = tid >> 6;       // 0..15
    const int lane = tid & 63;
    const int nb = blockIdx.x * 16;  // 3125 blocks exact
    {
        const int n = nb + wave;
        const int f = lane * 2;
        const int rs = rowst[n];
        const int re = rowst[n + 1];
        const float di = dinv[n];
        const float2 bb = *(const float2*)(bias + f);
        const float2 r = gather_node(rs, re, csr_s, Bin, dinv, di, n, bb, f);
        ushort2 o; o.x = f2b(r.x); o.y = f2b(r.y);
        *(ushort2*)&sA[wave][f] = o;
    }
    __syncthreads();
    if (wave >= 8) return;
    const int ct = wave;
    const int m = lane & 15;
    const int q = lane >> 4;
    f32x4 acc = (f32x4){0.f, 0.f, 0.f, 0.f};
    const u16* wrow = WTn + (size_t)m * FD + q * 8 + (size_t)ct * 16 * FD;
#pragma unroll
    for (int kb = 0; kb < 4; ++kb) {
        bf16x8 af = *(const bf16x8*)&sA[m][q * 8 + kb * 32];
        bf16x8 bf = *(const bf16x8*)(wrow + kb * 32);
        acc = __builtin_amdgcn_mfma_f32_16x16x32_bf16(af, bf, acc, 0, 0, 0);
    }
#pragma unroll
    for (int r = 0; r < 4; ++r)
        Bout[(size_t)(nb + q * 4 + r) * FD + ct * 16 + m] = f2b(acc[r]);
}

// ======== final gather (layer 2) -> Ab bf16 ========
__global__ __launch_bounds__(256) void k_gather(const int* __restrict__ rowst,
                                                const int* __restrict__ csr_s,
                                                const u16* __restrict__ B,
                                                const float* __restrict__ dinv,
                                                const float* __restrict__ bias,
                                                u16* __restrict__ Ab) {
    const int gid = blockIdx.x * 256 + threadIdx.x;   // NN*64 threads exact
    const int n = gid >> 6;
    const int f = (gid & 63) * 2;
    const int rs = rowst[n];
    const int re = rowst[n + 1];
    const float di = dinv[n];
    const float2 bb = *(const float2*)(bias + f);
    const float2 r = gather_node(rs, re, csr_s, B, dinv, di, n, bb, f);
    ushort2 o; o.x = f2b(r.x); o.y = f2b(r.y);
    *(ushort2*)(Ab + (size_t)n * FD + f) = o;
}

// ======== fused mean-pool + linear head + log_softmax (1 block / graph) ====
__global__ __launch_bounds__(256) void k_poolhead(const u16* __restrict__ Ab,
                                                  const int* __restrict__ batch,
                                                  const float* __restrict__ lin_w,
                                                  const float* __restrict__ lin_b,
                                                  float* __restrict__ out) {
    __shared__ float sb[256];
    __shared__ float hm[FD];
    __shared__ int bnd[2];
    __shared__ float part2[2 * NC];
    const int g = blockIdx.x;                          // NG blocks
    const int tid = threadIdx.x;
    if (tid < 2) {
        const int key = g + tid;
        int lo = 0, hi = NN;
        while (lo < hi) {
            const int mid = (lo + hi) >> 1;
            if (batch[mid] < key) lo = mid + 1; else hi = mid;
        }
        bnd[tid] = lo;
    }
    __syncthreads();
    const int r0 = bnd[0], r1 = bnd[1];
    const int f = tid & 127;
    const int half = tid >> 7;
    float acc = 0.f;
    for (int r = r0 + half; r < r1; r += 2)
        acc += b2f(Ab[(size_t)r * FD + f]);
    sb[tid] = acc;
    __syncthreads();
    if (tid < 128) {
        const float mean = (sb[tid] + sb[tid + 128]) /
                           fmaxf((float)(r1 - r0), 1.0f);
        hm[tid] = mean;
        out[(size_t)g * FD + tid] = mean;
    }
    __syncthreads();
    if (tid < 128) {
        const float hv = hm[tid];
        const int wv = tid >> 6;
#pragma unroll
        for (int c = 0; c < NC; ++c) {
            float p = hv * lin_w[tid * NC + c];
#pragma unroll
            for (int o = 32; o > 0; o >>= 1) p += __shfl_down(p, o, 64);
            if ((tid & 63) == 0) part2[c * 2 + wv] = p;
        }
    }
    __syncthreads();
    if (tid == 0) {
        float lg[NC];
        float m = -1e30f;
#pragma unroll
        for (int c = 0; c < NC; ++c) {
            lg[c] = part2[2 * c] + part2[2 * c + 1] + lin_b[c];
            m = fmaxf(m, lg[c]);
        }
        float s = 0.f;
#pragma unroll
        for (int c = 0; c < NC; ++c) s += expf(lg[c] - m);
        const float lse = m + logf(s);
        float* o = out + (size_t)NG * FD + (size_t)g * NC;
#pragma unroll
        for (int c = 0; c < NC; ++c) o[c] = lg[c] - lse;
    }
}

extern "C" void kernel_launch(void* const* d_in, const int* in_sizes, int n_in,
                              void* d_out, int out_size, void* d_ws, size_t ws_size,
                              hipStream_t stream) {
    const float* x     = (const float*)d_in[0];   // [NN,128] fp32
    const float* W     = (const float*)d_in[1];   // [3,128,128] fp32
    const float* bias  = (const float*)d_in[2];   // [3,128] fp32
    const float* lin_w = (const float*)d_in[3];   // [128,10] fp32
    const float* lin_b = (const float*)d_in[4];   // [10] fp32
    const int*   src   = (const int*)d_in[5];     // edge_index[0], int32
    const int*   dst   = src + NE;                // edge_index[1]
    const int*   batch = (const int*)d_in[6];     // [NN] int32

    // workspace layout (~43 MB), all chunks 16B-aligned
    u16*   B0     = (u16*)d_ws;                       // NN*FD bf16
    u16*   B1     = B0 + (size_t)NN * FD;             // NN*FD bf16
    u16*   Ab     = B1 + (size_t)NN * FD;             // NN*FD bf16 (final h)
    u16*   WT     = Ab + (size_t)NN * FD;             // NL*FD*FD bf16 (transposed)
    int*   csr_s  = (int*)(WT + (size_t)NL * FD * FD); // NE src-only
    int*   deg    = csr_s + NE;                       // NN
    int*   rowst  = deg + NN;                         // NN+1 (+3 pad)
    int*   pos    = rowst + NN + 4;                   // NN
    int*   agg    = pos + NN;                         // 256 (lookback aggregates)
    float* dinv   = (float*)(agg + 256);              // NN
    float* out    = (float*)d_out;                    // hG [NG*FD] ++ logsm [NG*NC]

    // --- CSR front-end: 4 dispatches, no grid-sync (R9/R10 lesson) ---
    k_prep<<<WT_B + SCAN_B + 1, 256, 0, stream>>>(W, WT, deg, agg);
    k_deg<<<NE / 256, 256, 0, stream>>>(dst, deg);
    k_scanf<<<SCAN_B, 256, 0, stream>>>(deg, dinv, agg, rowst, pos);
    k_fillgemm<<<FILL_B + GEMM_B, 256, 0, stream>>>(src, dst, pos, csr_s,
                                                    x, WT, B0);

    // --- layers: fused gather+gemm x2; final gather ---
    k_gg<<<NN / 16, 1024, 0, stream>>>(rowst, csr_s, B0, dinv, bias,
                                       WT + (size_t)1 * FD * FD, B1);
    k_gg<<<NN / 16, 1024, 0, stream>>>(rowst, csr_s, B1, dinv, bias + FD,
                                       WT + (size_t)2 * FD * FD, B0);
    k_gather<<<NN * 64 / 256, 256, 0, stream>>>(rowst, csr_s, B0, dinv,
                                                bias + 2 * FD, Ab);

    // --- fused mean pool + head ---
    k_poolhead<<<NG, 256, 0, stream>>>(Ab, batch, lin_w, lin_b, out);
}

// Round 12
// 373.320 us; speedup vs baseline: 2.9789x; 1.0255x over previous
//
#include <hip/hip_runtime.h>
#include <hip/hip_bf16.h>

// Problem constants (fixed by the reference setup)
#define NN 50000     // nodes
#define NE 800000    // edges
#define FD 128       // feature dim (D_FEAT == DIM_H)
#define NG 512       // graphs
#define NC 10        // classes
#define NL 3         // layers
#define SCAN_B 196   // ceil(NN/256)
#define WT_B 192     // NL*FD*FD/256
#define E4_B 782     // ceil(NE/1024) (4 edges/thread)
#define GEMM_B 782   // ceil(3125/4)

typedef unsigned short u16;
typedef unsigned int u32;
typedef short bf16x8 __attribute__((ext_vector_type(8)));
typedef float f32x4 __attribute__((ext_vector_type(4)));

__device__ __forceinline__ float b2f(u16 v) {
    union { u32 u; float f; } c; c.u = ((u32)v) << 16; return c.f;
}
__device__ __forceinline__ u16 f2b(float f) {
    __hip_bfloat16 h = __float2bfloat16(f);   // RTNE
    return *(u16*)&h;
}

// ======== zero deg + init lookback aggregates (lean, tiny) ========
__global__ __launch_bounds__(256) void k_zero(int* __restrict__ deg,
                                              int* __restrict__ agg) {
    const int bid = blockIdx.x;
    if (bid < SCAN_B) {
        const int n = bid * 256 + threadIdx.x;
        if (n < NN) deg[n] = 0;
    } else {
        if (threadIdx.x < SCAN_B) agg[threadIdx.x] = -1;
    }
}

// ======== deg atomics (4 edges/thread) + WT convert — both LEAN ========
// R9/R11 rule: fuse only phases of similar register weight.
__global__ __launch_bounds__(256) void k_degcvt(const int* __restrict__ dst,
                                                int* __restrict__ deg,
                                                const float* __restrict__ W,
                                                u16* __restrict__ wt) {
    const int bid = blockIdx.x;
    if (bid < E4_B) {
        const int e = (bid * 256 + threadIdx.x) * 4;
        if (e + 4 <= NE) {
            const int4 d4 = *(const int4*)(dst + e);
            atomicAdd(&deg[d4.x], 1);
            atomicAdd(&deg[d4.y], 1);
            atomicAdd(&deg[d4.z], 1);
            atomicAdd(&deg[d4.w], 1);
        } else {
            for (int j = 0; j < 4 && e + j < NE; ++j)
                atomicAdd(&deg[dst[e + j]], 1);
        }
    } else {
        const int i = (bid - E4_B) * 256 + threadIdx.x;   // NL*FD*FD exact
        const int l = i >> 14, r = i & 16383, k = r >> 7, n = r & 127;
        wt[(l << 14) + n * FD + k] = f2b(W[i]);
    }
}

// ======== gemm0 tile body: 16 rows of x(fp32) @ W0 -> B0(bf16) ========
// a_frag: A[m=lane&15][k=q*8+j]; b_frag: W[k=q*8+j][n=lane&15];
// C/D: col=lane&15, row=q*4+reg   [verified m89/m91; rounds 6-11]
__device__ __forceinline__ void gemm0_tile(const int row0, const int lane,
                                           const float* __restrict__ x,
                                           const u16* __restrict__ WT,
                                           u16* __restrict__ Bout) {
    const int m = lane & 15;
    const int q = lane >> 4;
    f32x4 acc[8];
#pragma unroll
    for (int ct = 0; ct < 8; ++ct) acc[ct] = (f32x4){0.f, 0.f, 0.f, 0.f};
    const float* arow = x + (size_t)(row0 + m) * FD + q * 8;
    const u16* wrow = WT + (size_t)m * FD + q * 8;
#pragma unroll
    for (int kb = 0; kb < 4; ++kb) {
        const float4 p0 = *(const float4*)(arow + kb * 32);
        const float4 p1 = *(const float4*)(arow + kb * 32 + 4);
        bf16x8 af;
        af[0] = (short)f2b(p0.x); af[1] = (short)f2b(p0.y);
        af[2] = (short)f2b(p0.z); af[3] = (short)f2b(p0.w);
        af[4] = (short)f2b(p1.x); af[5] = (short)f2b(p1.y);
        af[6] = (short)f2b(p1.z); af[7] = (short)f2b(p1.w);
#pragma unroll
        for (int ct = 0; ct < 8; ++ct) {
            bf16x8 bf = *(const bf16x8*)(wrow + (size_t)ct * 16 * FD + kb * 32);
            acc[ct] = __builtin_amdgcn_mfma_f32_16x16x32_bf16(af, bf, acc[ct], 0, 0, 0);
        }
    }
#pragma unroll
    for (int ct = 0; ct < 8; ++ct)
#pragma unroll
        for (int r = 0; r < 4; ++r)
            Bout[(size_t)(row0 + q * 4 + r) * FD + ct * 16 + m] = f2b(acc[ct][r]);
}

// ======== lookback scan (blocks 0..195, dispatched first => co-resident)
//          + gemm0 (blocks 196.., independent of the scan) ========
__global__ __launch_bounds__(256) void k_scangemm(const int* __restrict__ deg,
                                                  float* __restrict__ dinv,
                                                  int* __restrict__ agg,
                                                  int* __restrict__ rowst,
                                                  int* __restrict__ pos,
                                                  const float* __restrict__ x,
                                                  const u16* __restrict__ WT,
                                                  u16* __restrict__ B0) {
    const int tid = threadIdx.x;
    const int bid = blockIdx.x;
    if (bid >= SCAN_B) {
        const int wid = (bid - SCAN_B) * 4 + (tid >> 6);
        if (wid < 3125) gemm0_tile(wid * 16, tid & 63, x, WT, B0);
        return;
    }
    __shared__ int sb[256];
    const int i = bid * 256 + tid;
    const int v = (i < NN) ? deg[i] : 0;
    if (i < NN) dinv[i] = rsqrtf((float)(v + 1));     // +1 = self loop
    sb[tid] = v;
    __syncthreads();
    for (int off = 1; off < 256; off <<= 1) {
        int t = (tid >= off) ? sb[tid - off] : 0;
        __syncthreads();
        sb[tid] += t;
        __syncthreads();
    }
    const int excl = sb[tid] - v;
    const int aggregate = sb[255];
    __syncthreads();
    if (tid == 0) atomicExch(&agg[bid], aggregate);   // publish
    int a = 0;
    if (tid < bid) {                                   // parallel lookback
        do { a = atomicAdd(&agg[tid], 0); } while (a < 0);
    }
    sb[tid] = a;
    __syncthreads();
    for (int off = 128; off > 0; off >>= 1) {
        if (tid < off) sb[tid] += sb[tid + off];
        __syncthreads();
    }
    const int prefix = sb[0];
    if (i < NN) {
        const int e0 = prefix + excl;
        rowst[i] = e0;
        pos[i] = e0;
    }
    if (i == 0) rowst[NN] = NE;   // every edge has a dst
}

// ======== CSR fill: 4 edges/thread, LEAN (VGPR ~12) ========
__global__ __launch_bounds__(256) void k_fill(const int* __restrict__ src,
                                              const int* __restrict__ dst,
                                              int* __restrict__ pos,
                                              int* __restrict__ csr_s) {
    const int e = (blockIdx.x * 256 + threadIdx.x) * 4;
    if (e + 4 <= NE) {
        const int4 s4 = *(const int4*)(src + e);
        const int4 d4 = *(const int4*)(dst + e);
        const int p0 = atomicAdd(&pos[d4.x], 1);
        const int p1 = atomicAdd(&pos[d4.y], 1);
        const int p2 = atomicAdd(&pos[d4.z], 1);
        const int p3 = atomicAdd(&pos[d4.w], 1);
        csr_s[p0] = s4.x;
        csr_s[p1] = s4.y;
        csr_s[p2] = s4.z;
        csr_s[p3] = s4.w;
    } else {
        for (int j = 0; j < 4 && e + j < NE; ++j) {
            const int s = src[e + j];
            const int slot = atomicAdd(&pos[dst[e + j]], 1);
            csr_s[slot] = s;
        }
    }
}

// ======== per-wave gather body: relu(di*(sum + di*self) + bias) ========
__device__ __forceinline__ float2 gather_node(const int rs, const int re,
                                              const int* __restrict__ csr_s,
                                              const u16* __restrict__ B,
                                              const float* __restrict__ dinv,
                                              const float di, const int n,
                                              const float2 bb, const int f) {
    const ushort2 vs = *(const ushort2*)(B + (size_t)n * FD + f);
    float a0 = 0.f, a1 = 0.f, b0 = 0.f, b1 = 0.f;
    float c0 = 0.f, c1 = 0.f, d0 = 0.f, d1 = 0.f;
    int e = rs;
    for (; e + 8 <= re; e += 8) {                     // 8-edge unroll for MLP
        int s[8]; float w[8]; ushort2 v[8];
#pragma unroll
        for (int j = 0; j < 8; ++j) s[j] = csr_s[e + j];
#pragma unroll
        for (int j = 0; j < 8; ++j) w[j] = dinv[s[j]];
#pragma unroll
        for (int j = 0; j < 8; ++j)
            v[j] = *(const ushort2*)(B + (size_t)s[j] * FD + f);
        a0 += b2f(v[0].x) * w[0]; a1 += b2f(v[0].y) * w[0];
        b0 += b2f(v[1].x) * w[1]; b1 += b2f(v[1].y) * w[1];
        c0 += b2f(v[2].x) * w[2]; c1 += b2f(v[2].y) * w[2];
        d0 += b2f(v[3].x) * w[3]; d1 += b2f(v[3].y) * w[3];
        a0 += b2f(v[4].x) * w[4]; a1 += b2f(v[4].y) * w[4];
        b0 += b2f(v[5].x) * w[5]; b1 += b2f(v[5].y) * w[5];
        c0 += b2f(v[6].x) * w[6]; c1 += b2f(v[6].y) * w[6];
        d0 += b2f(v[7].x) * w[7]; d1 += b2f(v[7].y) * w[7];
    }
    for (; e + 4 <= re; e += 4) {
        int s[4]; float w[4]; ushort2 v[4];
#pragma unroll
        for (int j = 0; j < 4; ++j) s[j] = csr_s[e + j];
#pragma unroll
        for (int j = 0; j < 4; ++j) w[j] = dinv[s[j]];
#pragma unroll
        for (int j = 0; j < 4; ++j)
            v[j] = *(const ushort2*)(B + (size_t)s[j] * FD + f);
        a0 += b2f(v[0].x) * w[0]; a1 += b2f(v[0].y) * w[0];
        b0 += b2f(v[1].x) * w[1]; b1 += b2f(v[1].y) * w[1];
        c0 += b2f(v[2].x) * w[2]; c1 += b2f(v[2].y) * w[2];
        d0 += b2f(v[3].x) * w[3]; d1 += b2f(v[3].y) * w[3];
    }
    for (; e < re; ++e) {
        const int s0 = csr_s[e];
        const float w0 = dinv[s0];
        const ushort2 v0 = *(const ushort2*)(B + (size_t)s0 * FD + f);
        a0 += b2f(v0.x) * w0; a1 += b2f(v0.y) * w0;
    }
    a0 += b0 + c0 + d0 + b2f(vs.x) * di;   // self loop: dinv[n]*B[n]
    a1 += b1 + c1 + d1 + b2f(vs.y) * di;
    float2 r;
    r.x = fmaxf(a0 * di + bb.x, 0.f);      // w_e = dinv[s]*dinv[n] folded
    r.y = fmaxf(a1 * di + bb.y, 0.f);
    return r;
}

// ======== fused gather(l) + gemm(l+1): 16 waves gather -> 8 waves MFMA ====
__global__ __launch_bounds__(1024) void k_gg(const int* __restrict__ rowst,
                                             const int* __restrict__ csr_s,
                                             const u16* __restrict__ Bin,
                                             const float* __restrict__ dinv,
                                             const float* __restrict__ bias,
                                             const u16* __restrict__ WTn,
                                             u16* __restrict__ Bout) {
    __shared__ u16 sA[16][FD + 8];   // +16B row pad: break 16-way LDS conflicts
    const int tid = threadIdx.x;
    const int wave = tid >> 6;       // 0..15
    const int lane = tid & 63;
    const int nb = blockIdx.x * 16;  // 3125 blocks exact
    {
        const int n = nb + wave;
        const int f = lane * 2;
        const int rs = rowst[n];
        const int re = rowst[n + 1];
        const float di = dinv[n];
        const float2 bb = *(const float2*)(bias + f);
        const float2 r = gather_node(rs, re, csr_s, Bin, dinv, di, n, bb, f);
        ushort2 o; o.x = f2b(r.x); o.y = f2b(r.y);
        *(ushort2*)&sA[wave][f] = o;
    }
    __syncthreads();
    if (wave >= 8) return;
    const int ct = wave;
    const int m = lane & 15;
    const int q = lane >> 4;
    f32x4 acc = (f32x4){0.f, 0.f, 0.f, 0.f};
    const u16* wrow = WTn + (size_t)m * FD + q * 8 + (size_t)ct * 16 * FD;
#pragma unroll
    for (int kb = 0; kb < 4; ++kb) {
        bf16x8 af = *(const bf16x8*)&sA[m][q * 8 + kb * 32];
        bf16x8 bf = *(const bf16x8*)(wrow + kb * 32);
        acc = __builtin_amdgcn_mfma_f32_16x16x32_bf16(af, bf, acc, 0, 0, 0);
    }
#pragma unroll
    for (int r = 0; r < 4; ++r)
        Bout[(size_t)(nb + q * 4 + r) * FD + ct * 16 + m] = f2b(acc[r]);
}

// ======== final gather (layer 2) -> Ab bf16 ========
__global__ __launch_bounds__(256) void k_gather(const int* __restrict__ rowst,
                                                const int* __restrict__ csr_s,
                                                const u16* __restrict__ B,
                                                const float* __restrict__ dinv,
                                                const float* __restrict__ bias,
                                                u16* __restrict__ Ab) {
    const int gid = blockIdx.x * 256 + threadIdx.x;   // NN*64 threads exact
    const int n = gid >> 6;
    const int f = (gid & 63) * 2;
    const int rs = rowst[n];
    const int re = rowst[n + 1];
    const float di = dinv[n];
    const float2 bb = *(const float2*)(bias + f);
    const float2 r = gather_node(rs, re, csr_s, B, dinv, di, n, bb, f);
    ushort2 o; o.x = f2b(r.x); o.y = f2b(r.y);
    *(ushort2*)(Ab + (size_t)n * FD + f) = o;
}

// ======== fused mean-pool + linear head + log_softmax (1 block / graph) ====
__global__ __launch_bounds__(256) void k_poolhead(const u16* __restrict__ Ab,
                                                  const int* __restrict__ batch,
                                                  const float* __restrict__ lin_w,
                                                  const float* __restrict__ lin_b,
                                                  float* __restrict__ out) {
    __shared__ float sb[256];
    __shared__ float hm[FD];
    __shared__ int bnd[2];
    __shared__ float part2[2 * NC];
    const int g = blockIdx.x;                          // NG blocks
    const int tid = threadIdx.x;
    if (tid < 2) {
        const int key = g + tid;
        int lo = 0, hi = NN;
        while (lo < hi) {
            const int mid = (lo + hi) >> 1;
            if (batch[mid] < key) lo = mid + 1; else hi = mid;
        }
        bnd[tid] = lo;
    }
    __syncthreads();
    const int r0 = bnd[0], r1 = bnd[1];
    const int f = tid & 127;
    const int half = tid >> 7;
    float acc = 0.f;
    for (int r = r0 + half; r < r1; r += 2)
        acc += b2f(Ab[(size_t)r * FD + f]);
    sb[tid] = acc;
    __syncthreads();
    if (tid < 128) {
        const float mean = (sb[tid] + sb[tid + 128]) /
                           fmaxf((float)(r1 - r0), 1.0f);
        hm[tid] = mean;
        out[(size_t)g * FD + tid] = mean;
    }
    __syncthreads();
    if (tid < 128) {
        const float hv = hm[tid];
        const int wv = tid >> 6;
#pragma unroll
        for (int c = 0; c < NC; ++c) {
            float p = hv * lin_w[tid * NC + c];
#pragma unroll
            for (int o = 32; o > 0; o >>= 1) p += __shfl_down(p, o, 64);
            if ((tid & 63) == 0) part2[c * 2 + wv] = p;
        }
    }
    __syncthreads();
    if (tid == 0) {
        float lg[NC];
        float m = -1e30f;
#pragma unroll
        for (int c = 0; c < NC; ++c) {
            lg[c] = part2[2 * c] + part2[2 * c + 1] + lin_b[c];
            m = fmaxf(m, lg[c]);
        }
        float s = 0.f;
#pragma unroll
        for (int c = 0; c < NC; ++c) s += expf(lg[c] - m);
        const float lse = m + logf(s);
        float* o = out + (size_t)NG * FD + (size_t)g * NC;
#pragma unroll
        for (int c = 0; c < NC; ++c) o[c] = lg[c] - lse;
    }
}

extern "C" void kernel_launch(void* const* d_in, const int* in_sizes, int n_in,
                              void* d_out, int out_size, void* d_ws, size_t ws_size,
                              hipStream_t stream) {
    const float* x     = (const float*)d_in[0];   // [NN,128] fp32
    const float* W     = (const float*)d_in[1];   // [3,128,128] fp32
    const float* bias  = (const float*)d_in[2];   // [3,128] fp32
    const float* lin_w = (const float*)d_in[3];   // [128,10] fp32
    const float* lin_b = (const float*)d_in[4];   // [10] fp32
    const int*   src   = (const int*)d_in[5];     // edge_index[0], int32
    const int*   dst   = src + NE;                // edge_index[1]
    const int*   batch = (const int*)d_in[6];     // [NN] int32

    // workspace layout (~43 MB), all chunks 16B-aligned
    u16*   B0     = (u16*)d_ws;                       // NN*FD bf16
    u16*   B1     = B0 + (size_t)NN * FD;             // NN*FD bf16
    u16*   Ab     = B1 + (size_t)NN * FD;             // NN*FD bf16 (final h)
    u16*   WT     = Ab + (size_t)NN * FD;             // NL*FD*FD bf16 (transposed)
    int*   csr_s  = (int*)(WT + (size_t)NL * FD * FD); // NE src-only
    int*   deg    = csr_s + NE;                       // NN
    int*   rowst  = deg + NN;                         // NN+1 (+3 pad)
    int*   pos    = rowst + NN + 4;                   // NN
    int*   agg    = pos + NN;                         // 256 (lookback aggregates)
    float* dinv   = (float*)(agg + 256);              // NN
    float* out    = (float*)d_out;                    // hG [NG*FD] ++ logsm [NG*NC]

    // --- front-end: 4 dispatches, no grid-sync, register-class-matched ---
    k_zero<<<SCAN_B + 1, 256, 0, stream>>>(deg, agg);
    k_degcvt<<<E4_B + WT_B, 256, 0, stream>>>(dst, deg, W, WT);
    k_scangemm<<<SCAN_B + GEMM_B, 256, 0, stream>>>(deg, dinv, agg, rowst, pos,
                                                    x, WT, B0);
    k_fill<<<E4_B, 256, 0, stream>>>(src, dst, pos, csr_s);

    // --- layers: fused gather+gemm x2; final gather ---
    k_gg<<<NN / 16, 1024, 0, stream>>>(rowst, csr_s, B0, dinv, bias,
                                       WT + (size_t)1 * FD * FD, B1);
    k_gg<<<NN / 16, 1024, 0, stream>>>(rowst, csr_s, B1, dinv, bias + FD,
                                       WT + (size_t)2 * FD * FD, B0);
    k_gather<<<NN * 64 / 256, 256, 0, stream>>>(rowst, csr_s, B0, dinv,
                                                bias + 2 * FD, Ab);

    // --- fused mean pool + head ---
    k_poolhead<<<NG, 256, 0, stream>>>(Ab, batch, lin_w, lin_b, out);
}

// Round 13
// 352.567 us; speedup vs baseline: 3.1543x; 1.0589x over previous
//
#include <hip/hip_runtime.h>
#include <hip/hip_bf16.h>

// Problem constants (fixed by the reference setup)
#define NN 50000     // nodes
#define NE 800000    // edges
#define FD 128       // feature dim (D_FEAT == DIM_H)
#define NG 512       // graphs
#define NC 10        // classes
#define NL 3         // layers
#define SCAN_B 196   // ceil(NN/256)
#define WT_B 192     // NL*FD*FD/256
#define E4_B 782     // ceil(NE/1024) (4 edges/thread)
#define GEMM_B 782   // ceil(3125/4)

typedef unsigned short u16;
typedef unsigned int u32;
typedef short bf16x8 __attribute__((ext_vector_type(8)));
typedef float f32x4 __attribute__((ext_vector_type(4)));

__device__ __forceinline__ float b2f(u16 v) {
    union { u32 u; float f; } c; c.u = ((u32)v) << 16; return c.f;
}
__device__ __forceinline__ u16 f2b(float f) {
    __hip_bfloat16 h = __float2bfloat16(f);   // RTNE
    return *(u16*)&h;
}

// ======== zero deg + init lookback aggregates (lean, tiny) ========
__global__ __launch_bounds__(256) void k_zero(int* __restrict__ deg,
                                              int* __restrict__ agg) {
    const int bid = blockIdx.x;
    if (bid < SCAN_B) {
        const int n = bid * 256 + threadIdx.x;
        if (n < NN) deg[n] = 0;
    } else {
        if (threadIdx.x < SCAN_B) agg[threadIdx.x] = -1;
    }
}

// ======== deg atomics (4 edges/thread) + WT convert — both LEAN ========
// R9/R11 rule: fuse only phases of similar register weight.
__global__ __launch_bounds__(256) void k_degcvt(const int* __restrict__ dst,
                                                int* __restrict__ deg,
                                                const float* __restrict__ W,
                                                u16* __restrict__ wt) {
    const int bid = blockIdx.x;
    if (bid < E4_B) {
        const int e = (bid * 256 + threadIdx.x) * 4;
        if (e + 4 <= NE) {
            const int4 d4 = *(const int4*)(dst + e);
            atomicAdd(&deg[d4.x], 1);
            atomicAdd(&deg[d4.y], 1);
            atomicAdd(&deg[d4.z], 1);
            atomicAdd(&deg[d4.w], 1);
        } else {
            for (int j = 0; j < 4 && e + j < NE; ++j)
                atomicAdd(&deg[dst[e + j]], 1);
        }
    } else {
        const int i = (bid - E4_B) * 256 + threadIdx.x;   // NL*FD*FD exact
        const int l = i >> 14, r = i & 16383, k = r >> 7, n = r & 127;
        wt[(l << 14) + n * FD + k] = f2b(W[i]);
    }
}

// ======== gemm0 tile body: 16 rows of x(fp32) @ W0 -> B0(bf16) ========
// a_frag: A[m=lane&15][k=q*8+j]; b_frag: W[k=q*8+j][n=lane&15];
// C/D: col=lane&15, row=q*4+reg   [verified m89/m91; rounds 6-12]
__device__ __forceinline__ void gemm0_tile(const int row0, const int lane,
                                           const float* __restrict__ x,
                                           const u16* __restrict__ WT,
                                           u16* __restrict__ Bout) {
    const int m = lane & 15;
    const int q = lane >> 4;
    f32x4 acc[8];
#pragma unroll
    for (int ct = 0; ct < 8; ++ct) acc[ct] = (f32x4){0.f, 0.f, 0.f, 0.f};
    const float* arow = x + (size_t)(row0 + m) * FD + q * 8;
    const u16* wrow = WT + (size_t)m * FD + q * 8;
#pragma unroll
    for (int kb = 0; kb < 4; ++kb) {
        const float4 p0 = *(const float4*)(arow + kb * 32);
        const float4 p1 = *(const float4*)(arow + kb * 32 + 4);
        bf16x8 af;
        af[0] = (short)f2b(p0.x); af[1] = (short)f2b(p0.y);
        af[2] = (short)f2b(p0.z); af[3] = (short)f2b(p0.w);
        af[4] = (short)f2b(p1.x); af[5] = (short)f2b(p1.y);
        af[6] = (short)f2b(p1.z); af[7] = (short)f2b(p1.w);
#pragma unroll
        for (int ct = 0; ct < 8; ++ct) {
            bf16x8 bf = *(const bf16x8*)(wrow + (size_t)ct * 16 * FD + kb * 32);
            acc[ct] = __builtin_amdgcn_mfma_f32_16x16x32_bf16(af, bf, acc[ct], 0, 0, 0);
        }
    }
#pragma unroll
    for (int ct = 0; ct < 8; ++ct)
#pragma unroll
        for (int r = 0; r < 4; ++r)
            Bout[(size_t)(row0 + q * 4 + r) * FD + ct * 16 + m] = f2b(acc[ct][r]);
}

// ======== lookback scan (blocks 0..195, dispatched first => co-resident)
//          + gemm0 (blocks 196.., independent of the scan) ========
__global__ __launch_bounds__(256) void k_scangemm(const int* __restrict__ deg,
                                                  float* __restrict__ dinv,
                                                  int* __restrict__ agg,
                                                  int* __restrict__ rowst,
                                                  int* __restrict__ pos,
                                                  const float* __restrict__ x,
                                                  const u16* __restrict__ WT,
                                                  u16* __restrict__ B0) {
    const int tid = threadIdx.x;
    const int bid = blockIdx.x;
    if (bid >= SCAN_B) {
        const int wid = (bid - SCAN_B) * 4 + (tid >> 6);
        if (wid < 3125) gemm0_tile(wid * 16, tid & 63, x, WT, B0);
        return;
    }
    __shared__ int sb[256];
    const int i = bid * 256 + tid;
    const int v = (i < NN) ? deg[i] : 0;
    if (i < NN) dinv[i] = rsqrtf((float)(v + 1));     // +1 = self loop
    sb[tid] = v;
    __syncthreads();
    for (int off = 1; off < 256; off <<= 1) {
        int t = (tid >= off) ? sb[tid - off] : 0;
        __syncthreads();
        sb[tid] += t;
        __syncthreads();
    }
    const int excl = sb[tid] - v;
    const int aggregate = sb[255];
    __syncthreads();
    if (tid == 0) atomicExch(&agg[bid], aggregate);   // publish
    int a = 0;
    if (tid < bid) {                                   // parallel lookback
        do { a = atomicAdd(&agg[tid], 0); } while (a < 0);
    }
    sb[tid] = a;
    __syncthreads();
    for (int off = 128; off > 0; off >>= 1) {
        if (tid < off) sb[tid] += sb[tid + off];
        __syncthreads();
    }
    const int prefix = sb[0];
    if (i < NN) {
        const int e0 = prefix + excl;
        rowst[i] = e0;
        pos[i] = e0;
    }
    if (i == 0) rowst[NN] = NE;   // every edge has a dst
}

// ======== CSR fill: 4 edges/thread, LEAN (VGPR ~12) ========
__global__ __launch_bounds__(256) void k_fill(const int* __restrict__ src,
                                              const int* __restrict__ dst,
                                              int* __restrict__ pos,
                                              int* __restrict__ csr_s) {
    const int e = (blockIdx.x * 256 + threadIdx.x) * 4;
    if (e + 4 <= NE) {
        const int4 s4 = *(const int4*)(src + e);
        const int4 d4 = *(const int4*)(dst + e);
        const int p0 = atomicAdd(&pos[d4.x], 1);
        const int p1 = atomicAdd(&pos[d4.y], 1);
        const int p2 = atomicAdd(&pos[d4.z], 1);
        const int p3 = atomicAdd(&pos[d4.w], 1);
        csr_s[p0] = s4.x;
        csr_s[p1] = s4.y;
        csr_s[p2] = s4.z;
        csr_s[p3] = s4.w;
    } else {
        for (int j = 0; j < 4 && e + j < NE; ++j) {
            const int s = src[e + j];
            const int slot = atomicAdd(&pos[dst[e + j]], 1);
            csr_s[slot] = s;
        }
    }
}

// ======== per-wave gather body: relu(di*(sum + di*self) + bias) ========
// 4-edge unroll: R8-proven sweet spot (VGPR ~24). 8-edge (R12) cost
// occupancy (VGPR 36, 62%->42%) and regressed k_gg 57->66 us.
__device__ __forceinline__ float2 gather_node(const int rs, const int re,
                                              const int* __restrict__ csr_s,
                                              const u16* __restrict__ B,
                                              const float* __restrict__ dinv,
                                              const float di, const int n,
                                              const float2 bb, const int f) {
    const ushort2 vs = *(const ushort2*)(B + (size_t)n * FD + f);
    float a0 = 0.f, a1 = 0.f, b0 = 0.f, b1 = 0.f;
    float c0 = 0.f, c1 = 0.f, d0 = 0.f, d1 = 0.f;
    int e = rs;
    for (; e + 4 <= re; e += 4) {
        const int s0 = csr_s[e];
        const int s1 = csr_s[e + 1];
        const int s2 = csr_s[e + 2];
        const int s3 = csr_s[e + 3];
        const float w0 = dinv[s0];
        const float w1 = dinv[s1];
        const float w2 = dinv[s2];
        const float w3 = dinv[s3];
        const ushort2 v0 = *(const ushort2*)(B + (size_t)s0 * FD + f);
        const ushort2 v1 = *(const ushort2*)(B + (size_t)s1 * FD + f);
        const ushort2 v2 = *(const ushort2*)(B + (size_t)s2 * FD + f);
        const ushort2 v3 = *(const ushort2*)(B + (size_t)s3 * FD + f);
        a0 += b2f(v0.x) * w0; a1 += b2f(v0.y) * w0;
        b0 += b2f(v1.x) * w1; b1 += b2f(v1.y) * w1;
        c0 += b2f(v2.x) * w2; c1 += b2f(v2.y) * w2;
        d0 += b2f(v3.x) * w3; d1 += b2f(v3.y) * w3;
    }
    for (; e < re; ++e) {
        const int s0 = csr_s[e];
        const float w0 = dinv[s0];
        const ushort2 v0 = *(const ushort2*)(B + (size_t)s0 * FD + f);
        a0 += b2f(v0.x) * w0; a1 += b2f(v0.y) * w0;
    }
    a0 += b0 + c0 + d0 + b2f(vs.x) * di;   // self loop: dinv[n]*B[n]
    a1 += b1 + c1 + d1 + b2f(vs.y) * di;
    float2 r;
    r.x = fmaxf(a0 * di + bb.x, 0.f);      // w_e = dinv[s]*dinv[n] folded
    r.y = fmaxf(a1 * di + bb.y, 0.f);
    return r;
}

// ======== fused gather(l) + gemm(l+1): 16 waves gather -> 8 waves MFMA ====
__global__ __launch_bounds__(1024) void k_gg(const int* __restrict__ rowst,
                                             const int* __restrict__ csr_s,
                                             const u16* __restrict__ Bin,
                                             const float* __restrict__ dinv,
                                             const float* __restrict__ bias,
                                             const u16* __restrict__ WTn,
                                             u16* __restrict__ Bout) {
    __shared__ u16 sA[16][FD + 8];   // +16B row pad: conflicts 2.8M -> 0.4M (R12)
    const int tid = threadIdx.x;
    const int wave = tid >> 6;       // 0..15
    const int lane = tid & 63;
    const int nb = blockIdx.x * 16;  // 3125 blocks exact
    {
        const int n = nb + wave;
        const int f = lane * 2;
        const int rs = rowst[n];
        const int re = rowst[n + 1];
        const float di = dinv[n];
        const float2 bb = *(const float2*)(bias + f);
        const float2 r = gather_node(rs, re, csr_s, Bin, dinv, di, n, bb, f);
        ushort2 o; o.x = f2b(r.x); o.y = f2b(r.y);
        *(ushort2*)&sA[wave][f] = o;
    }
    __syncthreads();
    if (wave >= 8) return;
    const int ct = wave;
    const int m = lane & 15;
    const int q = lane >> 4;
    f32x4 acc = (f32x4){0.f, 0.f, 0.f, 0.f};
    const u16* wrow = WTn + (size_t)m * FD + q * 8 + (size_t)ct * 16 * FD;
#pragma unroll
    for (int kb = 0; kb < 4; ++kb) {
        bf16x8 af = *(const bf16x8*)&sA[m][q * 8 + kb * 32];
        bf16x8 bf = *(const bf16x8*)(wrow + kb * 32);
        acc = __builtin_amdgcn_mfma_f32_16x16x32_bf16(af, bf, acc, 0, 0, 0);
    }
#pragma unroll
    for (int r = 0; r < 4; ++r)
        Bout[(size_t)(nb + q * 4 + r) * FD + ct * 16 + m] = f2b(acc[r]);
}

// ======== final gather (layer 2) -> Ab bf16 ========
__global__ __launch_bounds__(256) void k_gather(const int* __restrict__ rowst,
                                                const int* __restrict__ csr_s,
                                                const u16* __restrict__ B,
                                                const float* __restrict__ dinv,
                                                const float* __restrict__ bias,
                                                u16* __restrict__ Ab) {
    const int gid = blockIdx.x * 256 + threadIdx.x;   // NN*64 threads exact
    const int n = gid >> 6;
    const int f = (gid & 63) * 2;
    const int rs = rowst[n];
    const int re = rowst[n + 1];
    const float di = dinv[n];
    const float2 bb = *(const float2*)(bias + f);
    const float2 r = gather_node(rs, re, csr_s, B, dinv, di, n, bb, f);
    ushort2 o; o.x = f2b(r.x); o.y = f2b(r.y);
    *(ushort2*)(Ab + (size_t)n * FD + f) = o;
}

// ======== fused mean-pool + linear head + log_softmax (1 block / graph) ====
__global__ __launch_bounds__(256) void k_poolhead(const u16* __restrict__ Ab,
                                                  const int* __restrict__ batch,
                                                  const float* __restrict__ lin_w,
                                                  const float* __restrict__ lin_b,
                                                  float* __restrict__ out) {
    __shared__ float sb[256];
    __shared__ float hm[FD];
    __shared__ int bnd[2];
    __shared__ float part2[2 * NC];
    const int g = blockIdx.x;                          // NG blocks
    const int tid = threadIdx.x;
    if (tid < 2) {
        const int key = g + tid;
        int lo = 0, hi = NN;
        while (lo < hi) {
            const int mid = (lo + hi) >> 1;
            if (batch[mid] < key) lo = mid + 1; else hi = mid;
        }
        bnd[tid] = lo;
    }
    __syncthreads();
    const int r0 = bnd[0], r1 = bnd[1];
    const int f = tid & 127;
    const int half = tid >> 7;
    float acc = 0.f;
    for (int r = r0 + half; r < r1; r += 2)
        acc += b2f(Ab[(size_t)r * FD + f]);
    sb[tid] = acc;
    __syncthreads();
    if (tid < 128) {
        const float mean = (sb[tid] + sb[tid + 128]) /
                           fmaxf((float)(r1 - r0), 1.0f);
        hm[tid] = mean;
        out[(size_t)g * FD + tid] = mean;
    }
    __syncthreads();
    if (tid < 128) {
        const float hv = hm[tid];
        const int wv = tid >> 6;
#pragma unroll
        for (int c = 0; c < NC; ++c) {
            float p = hv * lin_w[tid * NC + c];
#pragma unroll
            for (int o = 32; o > 0; o >>= 1) p += __shfl_down(p, o, 64);
            if ((tid & 63) == 0) part2[c * 2 + wv] = p;
        }
    }
    __syncthreads();
    if (tid == 0) {
        float lg[NC];
        float m = -1e30f;
#pragma unroll
        for (int c = 0; c < NC; ++c) {
            lg[c] = part2[2 * c] + part2[2 * c + 1] + lin_b[c];
            m = fmaxf(m, lg[c]);
        }
        float s = 0.f;
#pragma unroll
        for (int c = 0; c < NC; ++c) s += expf(lg[c] - m);
        const float lse = m + logf(s);
        float* o = out + (size_t)NG * FD + (size_t)g * NC;
#pragma unroll
        for (int c = 0; c < NC; ++c) o[c] = lg[c] - lse;
    }
}

extern "C" void kernel_launch(void* const* d_in, const int* in_sizes, int n_in,
                              void* d_out, int out_size, void* d_ws, size_t ws_size,
                              hipStream_t stream) {
    const float* x     = (const float*)d_in[0];   // [NN,128] fp32
    const float* W     = (const float*)d_in[1];   // [3,128,128] fp32
    const float* bias  = (const float*)d_in[2];   // [3,128] fp32
    const float* lin_w = (const float*)d_in[3];   // [128,10] fp32
    const float* lin_b = (const float*)d_in[4];   // [10] fp32
    const int*   src   = (const int*)d_in[5];     // edge_index[0], int32
    const int*   dst   = src + NE;                // edge_index[1]
    const int*   batch = (const int*)d_in[6];     // [NN] int32

    // workspace layout (~43 MB), all chunks 16B-aligned
    u16*   B0     = (u16*)d_ws;                       // NN*FD bf16
    u16*   B1     = B0 + (size_t)NN * FD;             // NN*FD bf16
    u16*   Ab     = B1 + (size_t)NN * FD;             // NN*FD bf16 (final h)
    u16*   WT     = Ab + (size_t)NN * FD;             // NL*FD*FD bf16 (transposed)
    int*   csr_s  = (int*)(WT + (size_t)NL * FD * FD); // NE src-only
    int*   deg    = csr_s + NE;                       // NN
    int*   rowst  = deg + NN;                         // NN+1 (+3 pad)
    int*   pos    = rowst + NN + 4;                   // NN
    int*   agg    = pos + NN;                         // 256 (lookback aggregates)
    float* dinv   = (float*)(agg + 256);              // NN
    float* out    = (float*)d_out;                    // hG [NG*FD] ++ logsm [NG*NC]

    // --- front-end: 4 dispatches, no grid-sync, register-class-matched ---
    k_zero<<<SCAN_B + 1, 256, 0, stream>>>(deg, agg);
    k_degcvt<<<E4_B + WT_B, 256, 0, stream>>>(dst, deg, W, WT);
    k_scangemm<<<SCAN_B + GEMM_B, 256, 0, stream>>>(deg, dinv, agg, rowst, pos,
                                                    x, WT, B0);
    k_fill<<<E4_B, 256, 0, stream>>>(src, dst, pos, csr_s);

    // --- layers: fused gather+gemm x2; final gather ---
    k_gg<<<NN / 16, 1024, 0, stream>>>(rowst, csr_s, B0, dinv, bias,
                                       WT + (size_t)1 * FD * FD, B1);
    k_gg<<<NN / 16, 1024, 0, stream>>>(rowst, csr_s, B1, dinv, bias + FD,
                                       WT + (size_t)2 * FD * FD, B0);
    k_gather<<<NN * 64 / 256, 256, 0, stream>>>(rowst, csr_s, B0, dinv,
                                                bias + 2 * FD, Ab);

    // --- fused mean pool + head ---
    k_poolhead<<<NG, 256, 0, stream>>>(Ab, batch, lin_w, lin_b, out);
}